// Round 1
// baseline (135.587 us; speedup 1.0000x reference)
//
#include <hip/hip_runtime.h>
#include <hip/hip_bf16.h>

// AvgPool2d 2x2 stride 2, count_include_pad semantics irrelevant (no padding).
// x: [32, 256, 128, 128] f32 -> out: [32, 256, 64, 64] f32.
//
// Mapping: one thread per float2 of output (2 adjacent output columns).
// Each thread loads one float4 from input row 2*oh and one float4 from row
// 2*oh+1 (contiguous 16B per lane, 1 KiB per wave per load instruction),
// computes two averages, stores one float2 (coalesced 8B/lane).

#define IN_W   128
#define IN_HW  (128 * 128)
#define OUT_W  64
#define OUT_HW (64 * 64)

__global__ __launch_bounds__(256) void avgpool2x2_kernel(
    const float* __restrict__ in, float* __restrict__ out, int n_units) {
    // n_units = total output elems / 2 (float2 units)
    int stride = gridDim.x * blockDim.x;
    for (int u = blockIdx.x * blockDim.x + threadIdx.x; u < n_units; u += stride) {
        int ow2 = u & 31;            // which float2 within the 64-wide output row
        int rest = u >> 5;
        int oh = rest & 63;
        int img = rest >> 6;         // fused (n, c) index, 0..8191

        const float* src = in + (size_t)img * IN_HW + (size_t)(2 * oh) * IN_W + ow2 * 4;
        float4 a = *reinterpret_cast<const float4*>(src);
        float4 b = *reinterpret_cast<const float4*>(src + IN_W);

        float2 r;
        r.x = (a.x + a.y + b.x + b.y) * 0.25f;
        r.y = (a.z + a.w + b.z + b.w) * 0.25f;
        *reinterpret_cast<float2*>(out + (size_t)u * 2) = r;
    }
}

extern "C" void kernel_launch(void* const* d_in, const int* in_sizes, int n_in,
                              void* d_out, int out_size, void* d_ws, size_t ws_size,
                              hipStream_t stream) {
    const float* x = (const float*)d_in[0];
    float* out = (float*)d_out;

    int n_units = out_size / 2;  // 33,554,432 / 2 = 16,777,216
    int block = 256;
    int grid = 4096;             // grid-stride; 4096*256 = 1,048,576 threads, 16 iters each
    avgpool2x2_kernel<<<grid, block, 0, stream>>>(x, out, n_units);
}

// Round 3
// 130.555 us; speedup vs baseline: 1.0385x; 1.0385x over previous
//
#include <hip/hip_runtime.h>
#include <hip/hip_bf16.h>

// AvgPool2d 2x2 stride 2, no padding.
// x: [32, 256, 128, 128] f32 -> out: [32, 256, 64, 64] f32.
//
// Mapping: one thread per float2 of output (2 adjacent output columns).
// Each thread loads one float4 from input row 2*oh and one from row 2*oh+1
// (contiguous 16B/lane), computes two averages, stores one float2.
//
// Exact division: n_units = 16,777,216 = GRID(4096) * BLOCK(256) * ITERS(16).
// Fixed trip count + partial unroll -> multiple independent load pairs in
// flight per wave, no per-iter bounds check. Nontemporal (streaming, zero
// reuse) via clang ext_vector types (HIP_vector_type not accepted by the
// nontemporal builtins).

typedef float f32x4 __attribute__((ext_vector_type(4)));
typedef float f32x2 __attribute__((ext_vector_type(2)));

#define IN_W   128
#define IN_HW  (128 * 128)

#define GRID   4096
#define BLOCK  256
#define ITERS  16

__global__ __launch_bounds__(BLOCK) void avgpool2x2_kernel(
    const float* __restrict__ in, float* __restrict__ out) {
    const int tid = blockIdx.x * BLOCK + threadIdx.x;
    const int stride = GRID * BLOCK;

#pragma unroll 4
    for (int it = 0; it < ITERS; ++it) {
        int u = tid + it * stride;

        int ow2 = u & 31;            // which float2 within the 64-wide output row
        int rest = u >> 5;
        int oh = rest & 63;
        int img = rest >> 6;         // fused (n, c) index, 0..8191

        const float* src = in + (size_t)img * IN_HW + (size_t)(2 * oh) * IN_W + ow2 * 4;
        f32x4 a = __builtin_nontemporal_load(reinterpret_cast<const f32x4*>(src));
        f32x4 b = __builtin_nontemporal_load(reinterpret_cast<const f32x4*>(src + IN_W));

        f32x2 r;
        r.x = (a.x + a.y + b.x + b.y) * 0.25f;
        r.y = (a.z + a.w + b.z + b.w) * 0.25f;
        __builtin_nontemporal_store(r, reinterpret_cast<f32x2*>(out + (size_t)u * 2));
    }
}

extern "C" void kernel_launch(void* const* d_in, const int* in_sizes, int n_in,
                              void* d_out, int out_size, void* d_ws, size_t ws_size,
                              hipStream_t stream) {
    const float* x = (const float*)d_in[0];
    float* out = (float*)d_out;

    // out_size = 32*256*64*64 = 33,554,432 -> 16,777,216 float2 units,
    // exactly GRID*BLOCK*ITERS.
    avgpool2x2_kernel<<<GRID, BLOCK, 0, stream>>>(x, out);
}